// Round 1
// baseline (1778.469 us; speedup 1.0000x reference)
//
#include <hip/hip_runtime.h>

#define N_NODES 500000
#define N_EDGES 8000000
#define N_GRAPHS 4096

// ---------------------------------------------------------------------------
// Edge kernel: per edge e, z = [x[dst], x[src], ea[e]] (6 floats),
// m = sigmoid(z@Wf+bf) * softplus(z@Ws+bs)  -> scatter-add into agg[dst].
// Grid is exactly E/256 blocks, so no bounds check (keeps weight loads in
// uniform control flow -> scalar loads).
// ---------------------------------------------------------------------------
__global__ __launch_bounds__(256) void edge_kernel(
    const float* __restrict__ x, const int* __restrict__ ei,
    const float* __restrict__ ea,
    const float* __restrict__ Wf, const float* __restrict__ bf,
    const float* __restrict__ Ws, const float* __restrict__ bs,
    float* __restrict__ agg)
{
    // Load tiny weights first (uniform -> s_load).
    float wf[12], ws[12];
#pragma unroll
    for (int i = 0; i < 12; ++i) { wf[i] = Wf[i]; ws[i] = Ws[i]; }
    float bf0 = bf[0], bf1 = bf[1], bs0 = bs[0], bs1 = bs[1];

    int e = blockIdx.x * 256 + threadIdx.x;
    int src = ei[e];
    int dst = ei[N_EDGES + e];
    float2 xd = *(const float2*)(x + 2 * (size_t)dst);
    float2 xs = *(const float2*)(x + 2 * (size_t)src);
    float2 ev = *(const float2*)(ea + 2 * (size_t)e);
    float z0 = xd.x, z1 = xd.y, z2 = xs.x, z3 = xs.y, z4 = ev.x, z5 = ev.y;

    float f0 = bf0 + z0*wf[0] + z1*wf[2] + z2*wf[4] + z3*wf[6] + z4*wf[8]  + z5*wf[10];
    float f1 = bf1 + z0*wf[1] + z1*wf[3] + z2*wf[5] + z3*wf[7] + z4*wf[9]  + z5*wf[11];
    float s0 = bs0 + z0*ws[0] + z1*ws[2] + z2*ws[4] + z3*ws[6] + z4*ws[8]  + z5*ws[10];
    float s1 = bs1 + z0*ws[1] + z1*ws[3] + z2*ws[5] + z3*ws[7] + z4*ws[9]  + z5*ws[11];

    float sig0 = 1.0f / (1.0f + __expf(-f0));
    float sig1 = 1.0f / (1.0f + __expf(-f1));
    float sp0  = fmaxf(s0, 0.0f) + __logf(1.0f + __expf(-fabsf(s0)));
    float sp1  = fmaxf(s1, 0.0f) + __logf(1.0f + __expf(-fabsf(s1)));

    float m0 = sig0 * sp0;
    float m1 = sig1 * sp1;

    float* p = agg + 2 * (size_t)dst;
    unsafeAtomicAdd(p,     m0);   // global_atomic_add_f32 (no CAS loop)
    unsafeAtomicAdd(p + 1, m1);
}

// ---------------------------------------------------------------------------
// Pool kernel: one 64-lane wave per graph. batch is sorted, so the node range
// of graph b is found by binary search; reduce relu((x+agg)@W1+b1) over the
// segment in registers, shuffle-reduce, write mean[b*3 + {0,1,2}].
// ---------------------------------------------------------------------------
__global__ __launch_bounds__(64) void pool_kernel(
    const float* __restrict__ x, const float* __restrict__ agg,
    const int* __restrict__ batch,
    const float* __restrict__ W1, const float* __restrict__ b1,
    float* __restrict__ mean_out)
{
    int b = blockIdx.x;

    float w00 = W1[0], w01 = W1[1], w02 = W1[2];
    float w10 = W1[3], w11 = W1[4], w12 = W1[5];
    float c0 = b1[0], c1 = b1[1], c2 = b1[2];

    // lower_bound(batch, b) and lower_bound(batch, b+1) — uniform search
    int lo = 0, hi = N_NODES;
    while (lo < hi) { int mid = (lo + hi) >> 1; if (batch[mid] < b) lo = mid + 1; else hi = mid; }
    int seg_s = lo;
    hi = N_NODES;
    while (lo < hi) { int mid = (lo + hi) >> 1; if (batch[mid] < b + 1) lo = mid + 1; else hi = mid; }
    int seg_e = lo;

    float a0 = 0.f, a1 = 0.f, a2 = 0.f;
    for (int i = seg_s + (int)threadIdx.x; i < seg_e; i += 64) {
        float h0 = x[2*(size_t)i]     + agg[2*(size_t)i];
        float h1 = x[2*(size_t)i + 1] + agg[2*(size_t)i + 1];
        a0 += fmaxf(h0*w00 + h1*w10 + c0, 0.f);
        a1 += fmaxf(h0*w01 + h1*w11 + c1, 0.f);
        a2 += fmaxf(h0*w02 + h1*w12 + c2, 0.f);
    }
#pragma unroll
    for (int off = 32; off; off >>= 1) {
        a0 += __shfl_down(a0, off);
        a1 += __shfl_down(a1, off);
        a2 += __shfl_down(a2, off);
    }
    if (threadIdx.x == 0) {
        float inv = 1.0f / fmaxf((float)(seg_e - seg_s), 1.0f);
        mean_out[3*(size_t)b]     = a0 * inv;
        mean_out[3*(size_t)b + 1] = a1 * inv;
        mean_out[3*(size_t)b + 2] = a2 * inv;
    }
}

// ---------------------------------------------------------------------------
// Final kernel: single block. y = relu([mean_a, mean_b] @ W2 + b2) per graph,
// write out[g]; LDS tree-reduce mean((y - target)^2) -> out[B].
// ---------------------------------------------------------------------------
__global__ __launch_bounds__(1024) void final_kernel(
    const float* __restrict__ ma, const float* __restrict__ mb,
    const float* __restrict__ W2, const float* __restrict__ b2,
    const float* __restrict__ targets,
    float* __restrict__ out)
{
    __shared__ float red[1024];
    float w0 = W2[0], w1 = W2[1], w2 = W2[2], w3 = W2[3], w4 = W2[4], w5 = W2[5];
    float bias = b2[0];

    float lsum = 0.f;
    for (int g = threadIdx.x; g < N_GRAPHS; g += 1024) {
        float v = bias
                + ma[3*(size_t)g]*w0 + ma[3*(size_t)g+1]*w1 + ma[3*(size_t)g+2]*w2
                + mb[3*(size_t)g]*w3 + mb[3*(size_t)g+1]*w4 + mb[3*(size_t)g+2]*w5;
        v = fmaxf(v, 0.f);
        out[g] = v;
        float d = v - targets[g];
        lsum += d * d;
    }
    red[threadIdx.x] = lsum;
    __syncthreads();
#pragma unroll
    for (int off = 512; off; off >>= 1) {
        if (threadIdx.x < (unsigned)off) red[threadIdx.x] += red[threadIdx.x + off];
        __syncthreads();
    }
    if (threadIdx.x == 0) out[N_GRAPHS] = red[0] * (1.0f / (float)N_GRAPHS);
}

extern "C" void kernel_launch(void* const* d_in, const int* in_sizes, int n_in,
                              void* d_out, int out_size, void* d_ws, size_t ws_size,
                              hipStream_t stream) {
    const float* x_a     = (const float*)d_in[0];
    const int*   ei_a    = (const int*)  d_in[1];
    const float* ea_a    = (const float*)d_in[2];
    const int*   batch_a = (const int*)  d_in[3];
    const float* x_b     = (const float*)d_in[4];
    const int*   ei_b    = (const int*)  d_in[5];
    const float* ea_b    = (const float*)d_in[6];
    const int*   batch_b = (const int*)  d_in[7];
    const float* targets = (const float*)d_in[8];
    // d_in[9] = num_graphs (compile-time constant N_GRAPHS)
    const float* Wf = (const float*)d_in[10];
    const float* bf = (const float*)d_in[11];
    const float* Ws = (const float*)d_in[12];
    const float* bs = (const float*)d_in[13];
    const float* W1 = (const float*)d_in[14];
    const float* b1 = (const float*)d_in[15];
    const float* W2 = (const float*)d_in[16];
    const float* b2 = (const float*)d_in[17];

    float* agg_a  = (float*)d_ws;                 // N*2
    float* agg_b  = agg_a + 2 * (size_t)N_NODES;  // N*2
    float* mean_a = agg_b + 2 * (size_t)N_NODES;  // B*3
    float* mean_b = mean_a + 3 * (size_t)N_GRAPHS;

    // Zero the two agg buffers (ws is poisoned 0xAA before every launch).
    hipMemsetAsync(d_ws, 0, 4 * (size_t)N_NODES * sizeof(float), stream);

    edge_kernel<<<N_EDGES / 256, 256, 0, stream>>>(x_a, ei_a, ea_a, Wf, bf, Ws, bs, agg_a);
    edge_kernel<<<N_EDGES / 256, 256, 0, stream>>>(x_b, ei_b, ea_b, Wf, bf, Ws, bs, agg_b);

    pool_kernel<<<N_GRAPHS, 64, 0, stream>>>(x_a, agg_a, batch_a, W1, b1, mean_a);
    pool_kernel<<<N_GRAPHS, 64, 0, stream>>>(x_b, agg_b, batch_b, W1, b1, mean_b);

    final_kernel<<<1, 1024, 0, stream>>>(mean_a, mean_b, W2, b2, targets, (float*)d_out);
}

// Round 2
// 920.186 us; speedup vs baseline: 1.9327x; 1.9327x over previous
//
#include <hip/hip_runtime.h>

#define N_NODES 500000
#define N_EDGES 8000000
#define N_GRAPHS 4096

// Fixed-point scale for packed-u64 atomic aggregation.
// m = sigmoid*softplus >= 0 always; per-edge m <~ 35, per-node sum <~ 330,
// so field_max ~ 330 * 2^22 = 1.4e9 < 2^32: the low field never carries
// into the high field. Quantization error ~1.2e-7 per edge.
#define FP_SCALE 4194304.0f         // 2^22
#define FP_INV   2.384185791015625e-07f  // 2^-22

// ---------------------------------------------------------------------------
// Edge kernel: per edge e, z = [x[dst], x[src], ea[e]] (6 floats),
// m = sigmoid(z@Wf+bf) * softplus(z@Ws+bs); pack m0,m1 as 2x u32 fixed-point
// into one u64 and scatter-add with a single global_atomic_add_x2.
// One atomic per edge (was two fp32) -> halves atomic transactions, which
// R1 counters showed to be the bottleneck (20 G trans/s, VALUBusy 3%).
// ---------------------------------------------------------------------------
__global__ __launch_bounds__(256) void edge_kernel(
    const float* __restrict__ x, const int* __restrict__ ei,
    const float* __restrict__ ea,
    const float* __restrict__ Wf, const float* __restrict__ bf,
    const float* __restrict__ Ws, const float* __restrict__ bs,
    unsigned long long* __restrict__ agg)
{
    // Load tiny weights first (uniform -> s_load).
    float wf[12], ws[12];
#pragma unroll
    for (int i = 0; i < 12; ++i) { wf[i] = Wf[i]; ws[i] = Ws[i]; }
    float bf0 = bf[0], bf1 = bf[1], bs0 = bs[0], bs1 = bs[1];

    int e = blockIdx.x * 256 + threadIdx.x;
    int src = ei[e];
    int dst = ei[N_EDGES + e];
    float2 xd = *(const float2*)(x + 2 * (size_t)dst);
    float2 xs = *(const float2*)(x + 2 * (size_t)src);
    float2 ev = *(const float2*)(ea + 2 * (size_t)e);
    float z0 = xd.x, z1 = xd.y, z2 = xs.x, z3 = xs.y, z4 = ev.x, z5 = ev.y;

    float f0 = bf0 + z0*wf[0] + z1*wf[2] + z2*wf[4] + z3*wf[6] + z4*wf[8]  + z5*wf[10];
    float f1 = bf1 + z0*wf[1] + z1*wf[3] + z2*wf[5] + z3*wf[7] + z4*wf[9]  + z5*wf[11];
    float s0 = bs0 + z0*ws[0] + z1*ws[2] + z2*ws[4] + z3*ws[6] + z4*ws[8]  + z5*ws[10];
    float s1 = bs1 + z0*ws[1] + z1*ws[3] + z2*ws[5] + z3*ws[7] + z4*ws[9]  + z5*ws[11];

    float sig0 = 1.0f / (1.0f + __expf(-f0));
    float sig1 = 1.0f / (1.0f + __expf(-f1));
    float sp0  = fmaxf(s0, 0.0f) + __logf(1.0f + __expf(-fabsf(s0)));
    float sp1  = fmaxf(s1, 0.0f) + __logf(1.0f + __expf(-fabsf(s1)));

    float m0 = sig0 * sp0;   // >= 0
    float m1 = sig1 * sp1;   // >= 0

    unsigned int fx0 = __float2uint_rn(m0 * FP_SCALE);
    unsigned int fx1 = __float2uint_rn(m1 * FP_SCALE);
    unsigned long long pk = (unsigned long long)fx0
                          | ((unsigned long long)fx1 << 32);

    atomicAdd(&agg[dst], pk);  // non-returning global_atomic_add_x2
}

// ---------------------------------------------------------------------------
// Pool kernel: one 64-lane wave per graph. batch is sorted, so the node range
// of graph b is found by binary search; reduce relu((x+agg)@W1+b1) over the
// segment in registers, shuffle-reduce, write mean[b*3 + {0,1,2}].
// agg is the packed fixed-point u64 array; decode on read.
// ---------------------------------------------------------------------------
__global__ __launch_bounds__(64) void pool_kernel(
    const float* __restrict__ x, const unsigned long long* __restrict__ agg,
    const int* __restrict__ batch,
    const float* __restrict__ W1, const float* __restrict__ b1,
    float* __restrict__ mean_out)
{
    int b = blockIdx.x;

    float w00 = W1[0], w01 = W1[1], w02 = W1[2];
    float w10 = W1[3], w11 = W1[4], w12 = W1[5];
    float c0 = b1[0], c1 = b1[1], c2 = b1[2];

    // lower_bound(batch, b) and lower_bound(batch, b+1) — uniform search
    int lo = 0, hi = N_NODES;
    while (lo < hi) { int mid = (lo + hi) >> 1; if (batch[mid] < b) lo = mid + 1; else hi = mid; }
    int seg_s = lo;
    hi = N_NODES;
    while (lo < hi) { int mid = (lo + hi) >> 1; if (batch[mid] < b + 1) lo = mid + 1; else hi = mid; }
    int seg_e = lo;

    float a0 = 0.f, a1 = 0.f, a2 = 0.f;
    for (int i = seg_s + (int)threadIdx.x; i < seg_e; i += 64) {
        unsigned long long v = agg[i];
        float g0 = (float)(unsigned int)(v & 0xffffffffull) * FP_INV;
        float g1 = (float)(unsigned int)(v >> 32) * FP_INV;
        float2 xv = *(const float2*)(x + 2 * (size_t)i);
        float h0 = xv.x + g0;
        float h1 = xv.y + g1;
        a0 += fmaxf(h0*w00 + h1*w10 + c0, 0.f);
        a1 += fmaxf(h0*w01 + h1*w11 + c1, 0.f);
        a2 += fmaxf(h0*w02 + h1*w12 + c2, 0.f);
    }
#pragma unroll
    for (int off = 32; off; off >>= 1) {
        a0 += __shfl_down(a0, off);
        a1 += __shfl_down(a1, off);
        a2 += __shfl_down(a2, off);
    }
    if (threadIdx.x == 0) {
        float inv = 1.0f / fmaxf((float)(seg_e - seg_s), 1.0f);
        mean_out[3*(size_t)b]     = a0 * inv;
        mean_out[3*(size_t)b + 1] = a1 * inv;
        mean_out[3*(size_t)b + 2] = a2 * inv;
    }
}

// ---------------------------------------------------------------------------
// Final kernel: single block. y = relu([mean_a, mean_b] @ W2 + b2) per graph,
// write out[g]; LDS tree-reduce mean((y - target)^2) -> out[B].
// ---------------------------------------------------------------------------
__global__ __launch_bounds__(1024) void final_kernel(
    const float* __restrict__ ma, const float* __restrict__ mb,
    const float* __restrict__ W2, const float* __restrict__ b2,
    const float* __restrict__ targets,
    float* __restrict__ out)
{
    __shared__ float red[1024];
    float w0 = W2[0], w1 = W2[1], w2 = W2[2], w3 = W2[3], w4 = W2[4], w5 = W2[5];
    float bias = b2[0];

    float lsum = 0.f;
    for (int g = threadIdx.x; g < N_GRAPHS; g += 1024) {
        float v = bias
                + ma[3*(size_t)g]*w0 + ma[3*(size_t)g+1]*w1 + ma[3*(size_t)g+2]*w2
                + mb[3*(size_t)g]*w3 + mb[3*(size_t)g+1]*w4 + mb[3*(size_t)g+2]*w5;
        v = fmaxf(v, 0.f);
        out[g] = v;
        float d = v - targets[g];
        lsum += d * d;
    }
    red[threadIdx.x] = lsum;
    __syncthreads();
#pragma unroll
    for (int off = 512; off; off >>= 1) {
        if (threadIdx.x < (unsigned)off) red[threadIdx.x] += red[threadIdx.x + off];
        __syncthreads();
    }
    if (threadIdx.x == 0) out[N_GRAPHS] = red[0] * (1.0f / (float)N_GRAPHS);
}

extern "C" void kernel_launch(void* const* d_in, const int* in_sizes, int n_in,
                              void* d_out, int out_size, void* d_ws, size_t ws_size,
                              hipStream_t stream) {
    const float* x_a     = (const float*)d_in[0];
    const int*   ei_a    = (const int*)  d_in[1];
    const float* ea_a    = (const float*)d_in[2];
    const int*   batch_a = (const int*)  d_in[3];
    const float* x_b     = (const float*)d_in[4];
    const int*   ei_b    = (const int*)  d_in[5];
    const float* ea_b    = (const float*)d_in[6];
    const int*   batch_b = (const int*)  d_in[7];
    const float* targets = (const float*)d_in[8];
    // d_in[9] = num_graphs (compile-time constant N_GRAPHS)
    const float* Wf = (const float*)d_in[10];
    const float* bf = (const float*)d_in[11];
    const float* Ws = (const float*)d_in[12];
    const float* bs = (const float*)d_in[13];
    const float* W1 = (const float*)d_in[14];
    const float* b1 = (const float*)d_in[15];
    const float* W2 = (const float*)d_in[16];
    const float* b2 = (const float*)d_in[17];

    unsigned long long* agg_a = (unsigned long long*)d_ws;        // N u64
    unsigned long long* agg_b = agg_a + (size_t)N_NODES;          // N u64
    float* mean_a = (float*)(agg_b + (size_t)N_NODES);            // B*3
    float* mean_b = mean_a + 3 * (size_t)N_GRAPHS;

    // Zero the two agg buffers (ws is poisoned 0xAA before every launch).
    hipMemsetAsync(d_ws, 0, 2 * (size_t)N_NODES * sizeof(unsigned long long), stream);

    edge_kernel<<<N_EDGES / 256, 256, 0, stream>>>(x_a, ei_a, ea_a, Wf, bf, Ws, bs, agg_a);
    edge_kernel<<<N_EDGES / 256, 256, 0, stream>>>(x_b, ei_b, ea_b, Wf, bf, Ws, bs, agg_b);

    pool_kernel<<<N_GRAPHS, 64, 0, stream>>>(x_a, agg_a, batch_a, W1, b1, mean_a);
    pool_kernel<<<N_GRAPHS, 64, 0, stream>>>(x_b, agg_b, batch_b, W1, b1, mean_b);

    final_kernel<<<1, 1024, 0, stream>>>(mean_a, mean_b, W2, b2, targets, (float*)d_out);
}